// Round 10
// baseline (2994.625 us; speedup 1.0000x reference)
//
#include <hip/hip_runtime.h>
#include <hip/hip_fp16.h>
#include <stdint.h>

typedef _Float16 half8 __attribute__((ext_vector_type(8)));
typedef float f32x4 __attribute__((ext_vector_type(4)));
typedef unsigned long long ull;

__device__ __forceinline__ uint16_t f2h(float f) {
    __half h = __float2half(f);
    return *reinterpret_cast<uint16_t*>(&h);
}
__device__ __forceinline__ float h2f(uint16_t b) {
    return (float)__builtin_bit_cast(_Float16, b);
}
__device__ __forceinline__ uint32_t pk2(float lo, float hi) {
    return (uint32_t)f2h(lo) | ((uint32_t)f2h(hi) << 16);
}
__device__ __forceinline__ float sigm(float v) {
    return __builtin_amdgcn_rcpf(1.f + __expf(-v));
}
__device__ __forceinline__ float tanhfast(float v) {
    float e = __expf(2.f * v);
    return 1.f - 2.f * __builtin_amdgcn_rcpf(e + 1.f);
}

// ==================== FAST PATH ====================
// ws layout: [0,65600) flags u32 [grp8][slice2][1025]
//            [65664, 65664+131072) hbuf ull [par2][grp8][slice2][m16][q32]
//            [262144, +268435456) xg f16x4-packed ull [grp][t][slice][m][u]
#define FL_BYTES 65600
#define HB_OFF   65664ull
#define XG_OFF   262144ull
#define WS_NEEDED (XG_OFF + 268435456ull)

__device__ __forceinline__ size_t HB(int par, int grp, int s, int m, int q) {
    return (((size_t)((par * 8 + grp) * 2 + s) * 16 + m) * 32 + q);
}
__device__ __forceinline__ size_t XGi(int grp, int t, int s, int m, int u) {
    return ((((size_t)(grp * 1024 + t) * 2 + s) * 16 + m) * 128 + u);
}

// ---- pregemm: xg[b,t,col] = x[b,t,:]@wx[:,col] + bias, packed 4 gates/ull ----
// grid 256 = tchunk16 x grp8 x slice2, 512 threads.
__global__ __launch_bounds__(512, 1) void xw_gemm(
    const float* __restrict__ x, const float* __restrict__ wx,
    const float* __restrict__ bias, ull* __restrict__ xg)
{
    const int tid = threadIdx.x;
    const int tc = blockIdx.x >> 4;
    const int grp = (blockIdx.x >> 1) & 7;
    const int slice = blockIdx.x & 1;
    const int lane = tid & 63, wave = tid >> 6;
    const int cw = lane & 15, lhi = lane >> 4;
    const int u = wave * 16 + cw;

    __shared__ __align__(16) uint16_t Wxl[512 * 136];       // 139264 B
    __shared__ __align__(16) uint16_t Xl[2][16][33][8];     // 16896 B

    half8 Wxf[4][8];
    #pragma unroll
    for (int p = 0; p < 2; ++p) {
        for (int idx = tid; idx < 512 * 128; idx += 512) {
            int k_l = idx >> 9, c_l = idx & 511;
            int gg = c_l >> 7, uu = c_l & 127;
            int col = gg * 256 + slice * 128 + uu;
            Wxl[c_l * 136 + k_l] = f2h(wx[(size_t)(p * 128 + k_l) * 1024 + col]);
        }
        __syncthreads();
        #pragma unroll
        for (int g = 0; g < 4; ++g)
            #pragma unroll
            for (int jj = 0; jj < 4; ++jj)
                Wxf[g][p * 4 + jj] = *reinterpret_cast<const half8*>(
                    &Wxl[(g * 128 + u) * 136 + jj * 32 + lhi * 8]);
        __syncthreads();
    }
    float bv[4];
    #pragma unroll
    for (int g = 0; g < 4; ++g) bv[g] = bias[g * 256 + slice * 128 + u];

    const int t0 = tc * 64;
    const int m_s = tid >> 5, q_s = tid & 31;
    const float* xrow = &x[((size_t)(grp * 16 + m_s) * 1024) * 256 + q_s * 8];
    {   // stage x(t0)
        const float4* xs = reinterpret_cast<const float4*>(xrow + (size_t)t0 * 256);
        float4 a = xs[0], b = xs[1];
        uint4 pkv = {pk2(a.x, a.y), pk2(a.z, a.w), pk2(b.x, b.y), pk2(b.z, b.w)};
        *reinterpret_cast<uint4*>(&Xl[0][m_s][q_s][0]) = pkv;
    }
    float4 xa, xb;
    {   // prefetch x(t0+1)
        const float4* xs = reinterpret_cast<const float4*>(xrow + (size_t)(t0 + 1) * 256);
        xa = xs[0]; xb = xs[1];
    }
    __syncthreads();

    for (int tt = 0; tt < 64; ++tt) {
        const int t = t0 + tt, buf = tt & 1, bn = buf ^ 1;
        if (tt < 63) {
            uint4 pkv = {pk2(xa.x, xa.y), pk2(xa.z, xa.w), pk2(xb.x, xb.y), pk2(xb.z, xb.w)};
            *reinterpret_cast<uint4*>(&Xl[bn][m_s][q_s][0]) = pkv;
        }
        if (tt < 62) {
            const float4* xs = reinterpret_cast<const float4*>(xrow + (size_t)(t + 2) * 256);
            xa = xs[0]; xb = xs[1];
        }
        f32x4 a0 = {0,0,0,0}, a1 = {0,0,0,0}, a2 = {0,0,0,0}, a3 = {0,0,0,0};
        #pragma unroll
        for (int ks = 0; ks < 8; ++ks) {
            half8 av = *reinterpret_cast<const half8*>(&Xl[buf][cw][ks * 4 + lhi][0]);
            a0 = __builtin_amdgcn_mfma_f32_16x16x32_f16(av, Wxf[0][ks], a0, 0, 0, 0);
            a1 = __builtin_amdgcn_mfma_f32_16x16x32_f16(av, Wxf[1][ks], a1, 0, 0, 0);
            a2 = __builtin_amdgcn_mfma_f32_16x16x32_f16(av, Wxf[2][ks], a2, 0, 0, 0);
            a3 = __builtin_amdgcn_mfma_f32_16x16x32_f16(av, Wxf[3][ks], a3, 0, 0, 0);
        }
        #pragma unroll
        for (int r = 0; r < 4; ++r) {
            ull v = (ull)f2h(a0[r] + bv[0])
                  | ((ull)f2h(a1[r] + bv[1]) << 16)
                  | ((ull)f2h(a2[r] + bv[2]) << 32)
                  | ((ull)f2h(a3[r] + bv[3]) << 48);
            xg[XGi(grp, t, slice, lhi * 4 + r, u)] = v;
        }
        __syncthreads();
    }
}

// ---- recurrence: 16 blocks = 8 groups x 2 slices; peer exchange via MALL ----
__global__ __launch_bounds__(512, 1) void lstm_pair(
    const float* __restrict__ h0, const float* __restrict__ c0,
    const float* __restrict__ wh, float* __restrict__ out,
    uint32_t* flags, ull* hbuf, const ull* __restrict__ xg)
{
    const int tid = threadIdx.x;
    const int grp = blockIdx.x >> 1;
    const int slice = blockIdx.x & 1;
    const int lane = tid & 63, wave = tid >> 6;
    const int cw = lane & 15, lhi = lane >> 4;
    const int u = wave * 16 + cw;         // 0..127 local unit
    const int gu = slice * 128 + u;       // global unit

    __shared__ __align__(16) uint16_t Whl[512 * 136];       // 139264 B (prologue)
    __shared__ __align__(16) uint16_t Hs2[2][16][33][8];    // 16896 B

    // Wf[g][j]: j 0..3 = own-k frags, 4..7 = peer-k frags
    half8 Wf[4][8];
    #pragma unroll
    for (int p = 0; p < 2; ++p) {
        for (int idx = tid; idx < 512 * 128; idx += 512) {
            int k_l = idx >> 9, c_l = idx & 511;
            int gg = c_l >> 7, uu = c_l & 127;
            int col = gg * 256 + slice * 128 + uu;
            Whl[c_l * 136 + k_l] = f2h(wh[(size_t)(p * 128 + k_l) * 1024 + col]);
        }
        __syncthreads();
        if (slice == p) {
            #pragma unroll
            for (int g = 0; g < 4; ++g)
                #pragma unroll
                for (int jj = 0; jj < 4; ++jj)
                    Wf[g][jj] = *reinterpret_cast<const half8*>(
                        &Whl[(g * 128 + u) * 136 + jj * 32 + lhi * 8]);
        } else {
            #pragma unroll
            for (int g = 0; g < 4; ++g)
                #pragma unroll
                for (int jj = 0; jj < 4; ++jj)
                    Wf[g][4 + jj] = *reinterpret_cast<const half8*>(
                        &Whl[(g * 128 + u) * 136 + jj * 32 + lhi * 8]);
        }
        __syncthreads();
    }

    const int m_s = tid >> 5, q_s = tid & 31;
    {   // stage FULL h(0) (own + peer halves, straight from global h0)
        const float4* hp = reinterpret_cast<const float4*>(
            &h0[(size_t)(grp * 16 + m_s) * 256 + q_s * 8]);
        float4 a = hp[0], b = hp[1];
        uint4 pkv = {pk2(a.x, a.y), pk2(a.z, a.w), pk2(b.x, b.y), pk2(b.z, b.w)};
        *reinterpret_cast<uint4*>(&Hs2[0][m_s][q_s][0]) = pkv;
    }
    float c_reg[4];
    #pragma unroll
    for (int r = 0; r < 4; ++r)
        c_reg[r] = c0[(size_t)(grp * 16 + lhi * 4 + r) * 256 + gu];

    const size_t xg_base = (size_t)grp * 4194304 + (size_t)slice * 2048 + (size_t)u;
    ull xq0 = xg[xg_base + (lhi * 4 + 0) * 128];
    ull xq1 = xg[xg_base + (lhi * 4 + 1) * 128];
    ull xq2 = xg[xg_base + (lhi * 4 + 2) * 128];
    ull xq3 = xg[xg_base + (lhi * 4 + 3) * 128];
    __syncthreads();

    uint32_t* flA = flags + (grp * 2 + slice) * 1025;
    uint32_t* flB = flags + (grp * 2 + (1 - slice)) * 1025;
    const int koA = slice * 16;         // own k-oct base
    const int koB = 16 - koA;           // peer k-oct base
    const int ko_w = gu >> 3, e_w = gu & 7;
    float* outrow0 = &out[((size_t)(grp * 16) * 1024) * 256 + gu];
    float hv[4] = {0.f, 0.f, 0.f, 0.f};

    for (int t = 0; t < 1024; ++t) {
        const int par = t & 1, pn = par ^ 1;

        // own-half hGEMM (hides peer's publish flight)
        f32x4 a0 = {0,0,0,0}, a1 = {0,0,0,0}, a2 = {0,0,0,0}, a3 = {0,0,0,0};
        #pragma unroll
        for (int jj = 0; jj < 4; ++jj) {
            half8 av = *reinterpret_cast<const half8*>(&Hs2[par][cw][koA + jj * 4 + lhi][0]);
            a0 = __builtin_amdgcn_mfma_f32_16x16x32_f16(av, Wf[0][jj], a0, 0, 0, 0);
            a1 = __builtin_amdgcn_mfma_f32_16x16x32_f16(av, Wf[1][jj], a1, 0, 0, 0);
            a2 = __builtin_amdgcn_mfma_f32_16x16x32_f16(av, Wf[2][jj], a2, 0, 0, 0);
            a3 = __builtin_amdgcn_mfma_f32_16x16x32_f16(av, Wf[3][jj], a3, 0, 0, 0);
        }
        asm volatile("s_waitcnt vmcnt(0)" ::: "memory");  // own publish(h(t)) drained
        __syncthreads();                                   // all waves drained
        if (t > 0 && tid == 0)
            __hip_atomic_store(&flA[t], 1u, __ATOMIC_RELAXED, __HIP_MEMORY_SCOPE_AGENT);

        // prefetch xg(t+1) (after the drain so it never blocks the flag)
        int tn = (t + 1 < 1024) ? t + 1 : t;
        const size_t xb = xg_base + (size_t)tn * 4096;
        ull nx0 = xg[xb + (lhi * 4 + 0) * 128];
        ull nx1 = xg[xb + (lhi * 4 + 1) * 128];
        ull nx2 = xg[xb + (lhi * 4 + 2) * 128];
        ull nx3 = xg[xb + (lhi * 4 + 3) * 128];

        if (t > 0) {
            // poll peer flag (broadcast line), then fetch peer half (8B/thread)
            while (__hip_atomic_load(&flB[t], __ATOMIC_RELAXED,
                                     __HIP_MEMORY_SCOPE_AGENT) == 0) {}
            ull pg = __hip_atomic_load(&hbuf[HB(par, grp, 1 - slice, m_s, q_s)],
                                       __ATOMIC_RELAXED, __HIP_MEMORY_SCOPE_AGENT);
            *reinterpret_cast<ull*>(&Hs2[par][m_s][koB + (q_s >> 1)][(q_s & 1) * 4]) = pg;
        }
        __syncthreads();   // peer half staged (t=0: from prologue)

        // peer-half hGEMM
        #pragma unroll
        for (int jj = 0; jj < 4; ++jj) {
            half8 av = *reinterpret_cast<const half8*>(&Hs2[par][cw][koB + jj * 4 + lhi][0]);
            a0 = __builtin_amdgcn_mfma_f32_16x16x32_f16(av, Wf[0][4 + jj], a0, 0, 0, 0);
            a1 = __builtin_amdgcn_mfma_f32_16x16x32_f16(av, Wf[1][4 + jj], a1, 0, 0, 0);
            a2 = __builtin_amdgcn_mfma_f32_16x16x32_f16(av, Wf[2][4 + jj], a2, 0, 0, 0);
            a3 = __builtin_amdgcn_mfma_f32_16x16x32_f16(av, Wf[3][4 + jj], a3, 0, 0, 0);
        }

        // gates + state update (all 4 gates of a unit live in-lane: no shuffles)
        #define GATES(r, xq)                                                        \
        {                                                                           \
            float tf = a0[r] + h2f((uint16_t)(xq));                                 \
            float ti = a1[r] + h2f((uint16_t)((xq) >> 16));                         \
            float to = a2[r] + h2f((uint16_t)((xq) >> 32));                         \
            float tg = a3[r] + h2f((uint16_t)((xq) >> 48));                         \
            float fg = sigm(tf), ig = sigm(ti), og = sigm(to), gv = tanhfast(tg);   \
            c_reg[r] = fmaf(c_reg[r], fg, gv * ig);                                 \
            hv[r] = tanhfast(c_reg[r]) * og;                                        \
        }
        GATES(0, xq0) GATES(1, xq1) GATES(2, xq2) GATES(3, xq3)
        #undef GATES

        // fullh (fire-and-forget; drained by next iteration's vmcnt(0))
        #pragma unroll
        for (int r = 0; r < 4; ++r)
            outrow0[((size_t)(lhi * 4 + r) * 1024 + t) * 256] = hv[r];

        // own h(t+1) -> LDS (2B writes, ~4-way on padded stride: cheap)
        #pragma unroll
        for (int r = 0; r < 4; ++r)
            Hs2[pn][lhi * 4 + r][ko_w][e_w] = f2h(hv[r]);
        __syncthreads();

        // publish own half as coalesced 8B granules
        {
            ull v = *reinterpret_cast<const ull*>(
                &Hs2[pn][m_s][koA + (q_s >> 1)][(q_s & 1) * 4]);
            __hip_atomic_store(&hbuf[HB(pn, grp, slice, m_s, q_s)], v,
                               __ATOMIC_RELAXED, __HIP_MEMORY_SCOPE_AGENT);
        }
        xq0 = nx0; xq1 = nx1; xq2 = nx2; xq3 = nx3;
    }

    // h_f, c_f
    const size_t fsz = (size_t)128 * 1024 * 256;
    #pragma unroll
    for (int r = 0; r < 4; ++r) {
        int b = grp * 16 + lhi * 4 + r;
        out[fsz + (size_t)b * 256 + gu] = hv[r];
        out[fsz + (size_t)128 * 256 + (size_t)b * 256 + gu] = c_reg[r];
    }
}

// ==================== FALLBACK (r6 verbatim, 2308 us) ====================
#define Tdim 1024
#define INdim 256
#define Hdim 256
#define COLS 1024
#define NSLICE 8
#define NGRP 8
#define GB 16
#define UPB 32
#define CPB 128
#define NTHREADS 512
#define FB_FLAG_STRIDE ((Tdim + 1) * NSLICE)
#define FB_FLAG_BYTES (NGRP * FB_FLAG_STRIDE * 4)
#define FB_HBUF_OFF 266240

__device__ __forceinline__ size_t hbF_idx(int par, int grp, int m, int u) {
    return ((((size_t)par * NGRP + grp) * GB + m) << 8) | (size_t)u;
}

__global__ __launch_bounds__(NTHREADS, 1) void lstm_fallback(
    const float* __restrict__ x, const float* __restrict__ h0,
    const float* __restrict__ c0, const float* __restrict__ wx,
    const float* __restrict__ wh, const float* __restrict__ bias,
    float* __restrict__ out, uint32_t* flags, uint16_t* hbuf)
{
    const int tid   = threadIdx.x;
    const int grp   = blockIdx.x & 7;
    const int slice = blockIdx.x >> 3;
    const int lane  = tid & 63;
    const int wave  = tid >> 6;
    const int cw    = lane & 15;
    const int lhi   = lane >> 4;
    const int cl    = wave * 16 + cw;
    const int g     = cl & 3;
    const int ul    = cl >> 2;
    const int u     = slice * UPB + ul;
    const int gcol  = g * Hdim + u;

    __shared__ __align__(16) uint16_t Wl[CPB * 512];
    __shared__ __align__(16) uint16_t X[2][GB][32][8];
    __shared__ __align__(16) uint16_t Hs[GB][32][8];
    __shared__ __align__(16) uint16_t Hp16[GB][UPB];
    __shared__ __align__(16) float    Hpf[GB][UPB];

    for (int idx = tid; idx < CPB * 512; idx += NTHREADS) {
        int k  = idx >> 7;
        int ci = idx & 127;
        int uu = ci & 31, gg = ci >> 5;
        int cg = gg * Hdim + slice * UPB + uu;
        int c  = (uu << 2) | gg;
        float w = (k < INdim) ? wx[(size_t)k * COLS + cg]
                              : wh[(size_t)(k - INdim) * COLS + cg];
        int e = c * 512 + ((((k >> 3) ^ (c & 7)) << 3) | (k & 7));
        Wl[e] = f2h(w);
    }
    const int m_s   = tid >> 5;
    const int ko_s  = tid & 31;
    const int slt_s = ko_s ^ (m_s & 7);
    {
        const float4* xs = reinterpret_cast<const float4*>(
            &x[((size_t)(grp * GB + m_s) * Tdim + 0) * INdim + ko_s * 8]);
        float4 a = xs[0], b = xs[1];
        uint4 pkv = {pk2(a.x, a.y), pk2(a.z, a.w), pk2(b.x, b.y), pk2(b.z, b.w)};
        *reinterpret_cast<uint4*>(&X[0][m_s][slt_s][0]) = pkv;
    }
    float4 xp0, xp1;
    {
        const float4* xs = reinterpret_cast<const float4*>(
            &x[((size_t)(grp * GB + m_s) * Tdim + 1) * INdim + ko_s * 8]);
        xp0 = xs[0]; xp1 = xs[1];
    }
    if (tid < 64) {
        int m = tid >> 2, uo = tid & 3;
        int u0 = slice * UPB + uo * 8;
        const float4* hs = reinterpret_cast<const float4*>(
            &h0[(size_t)(grp * GB + m) * Hdim + u0]);
        float4 a = hs[0], b = hs[1];
        ull p0 = (ull)pk2(a.x, a.y) | ((ull)pk2(a.z, a.w) << 32);
        ull p1 = (ull)pk2(b.x, b.y) | ((ull)pk2(b.z, b.w) << 32);
        ull* hp = reinterpret_cast<ull*>(&hbuf[hbF_idx(0, grp, m, u0)]);
        __hip_atomic_store(&hp[0], p0, __ATOMIC_RELAXED, __HIP_MEMORY_SCOPE_AGENT);
        __hip_atomic_store(&hp[1], p1, __ATOMIC_RELAXED, __HIP_MEMORY_SCOPE_AGENT);
    }
    float c_reg[4];
    #pragma unroll
    for (int r = 0; r < 4; ++r)
        c_reg[r] = c0[(size_t)(grp * GB + lhi * 4 + r) * Hdim + u];
    const float bv = bias[gcol];
    __syncthreads();
    uint32_t* fl = flags + grp * FB_FLAG_STRIDE;
    if (tid == 0)
        __hip_atomic_store(&fl[slice], 1u, __ATOMIC_RELAXED, __HIP_MEMORY_SCOPE_AGENT);

    const uint32_t swz = (uint32_t)(cl & 7);
    const uint16_t* wrow = &Wl[cl * 512];
    half8 Wf[16];
    #pragma unroll
    for (int i = 0; i < 16; ++i)
        Wf[i] = *reinterpret_cast<const half8*>(&wrow[(((uint32_t)(i * 4 + lhi)) ^ swz) << 3]);

    const int swz_a = cw & 7;
    float hv[4] = {0.f, 0.f, 0.f, 0.f};

    for (int t = 0; t < Tdim; ++t) {
        const int par = t & 1, pn = par ^ 1;
        {
            uint4 pkv = {pk2(xp0.x, xp0.y), pk2(xp0.z, xp0.w),
                         pk2(xp1.x, xp1.y), pk2(xp1.z, xp1.w)};
            *reinterpret_cast<uint4*>(&X[pn][m_s][slt_s][0]) = pkv;
        }
        {
            int tn = (t + 2 < Tdim) ? t + 2 : Tdim - 1;
            const float4* xs = reinterpret_cast<const float4*>(
                &x[((size_t)(grp * GB + m_s) * Tdim + tn) * INdim + ko_s * 8]);
            xp0 = xs[0]; xp1 = xs[1];
        }
        f32x4 acc0 = {0.f, 0.f, 0.f, 0.f}, acc1 = {0.f, 0.f, 0.f, 0.f};
        #pragma unroll
        for (int s = 0; s < 8; s += 2) {
            int ko0 = s * 4 + lhi, ko1 = ko0 + 4;
            half8 av0 = *reinterpret_cast<const half8*>(&X[par][cw][ko0 ^ swz_a][0]);
            acc0 = __builtin_amdgcn_mfma_f32_16x16x32_f16(av0, Wf[s], acc0, 0, 0, 0);
            half8 av1 = *reinterpret_cast<const half8*>(&X[par][cw][ko1 ^ swz_a][0]);
            acc1 = __builtin_amdgcn_mfma_f32_16x16x32_f16(av1, Wf[s + 1], acc1, 0, 0, 0);
        }
        if (tid < NSLICE) {
            while (__hip_atomic_load(&fl[t * NSLICE + tid], __ATOMIC_RELAXED,
                                     __HIP_MEMORY_SCOPE_AGENT) == 0) {}
        }
        __syncthreads();
        {
            const ull* hp = reinterpret_cast<const ull*>(
                &hbuf[hbF_idx(par, grp, m_s, ko_s * 8)]);
            ull h0v = __hip_atomic_load(&hp[0], __ATOMIC_RELAXED, __HIP_MEMORY_SCOPE_AGENT);
            ull h1v = __hip_atomic_load(&hp[1], __ATOMIC_RELAXED, __HIP_MEMORY_SCOPE_AGENT);
            uint4 hw = {(uint32_t)h0v, (uint32_t)(h0v >> 32),
                        (uint32_t)h1v, (uint32_t)(h1v >> 32)};
            *reinterpret_cast<uint4*>(&Hs[m_s][slt_s][0]) = hw;
        }
        __syncthreads();
        #pragma unroll
        for (int s = 0; s < 8; s += 2) {
            int ko0 = s * 4 + lhi, ko1 = ko0 + 4;
            half8 av0 = *reinterpret_cast<const half8*>(&Hs[cw][ko0 ^ swz_a][0]);
            acc0 = __builtin_amdgcn_mfma_f32_16x16x32_f16(av0, Wf[8 + s], acc0, 0, 0, 0);
            half8 av1 = *reinterpret_cast<const half8*>(&Hs[cw][ko1 ^ swz_a][0]);
            acc1 = __builtin_amdgcn_mfma_f32_16x16x32_f16(av1, Wf[9 + s], acc1, 0, 0, 0);
        }
        #pragma unroll
        for (int r = 0; r < 4; ++r) {
            float tval = acc0[r] + acc1[r] + bv;
            float act = (g == 3) ? tanhfast(tval) : sigm(tval);
            float x1  = __shfl_xor(act, 1);
            float e0  = (g & 1) ? x1 : act;
            float o1  = (g & 1) ? act : x1;
            float e0s = __shfl_xor(e0, 2);
            float o1s = __shfl_xor(o1, 2);
            float f_ = (g < 2) ? e0  : e0s;
            float i_ = (g < 2) ? o1  : o1s;
            float o_ = (g < 2) ? e0s : e0;
            float g_ = (g < 2) ? o1s : o1;
            c_reg[r] = fmaf(c_reg[r], f_, g_ * i_);
            hv[r] = tanhfast(c_reg[r]) * o_;
        }
        if (g == 0) {
            #pragma unroll
            for (int r = 0; r < 4; ++r) {
                int m = lhi * 4 + r;
                Hp16[m][ul] = f2h(hv[r]);
                Hpf[m][ul]  = hv[r];
            }
        }
        __syncthreads();
        if (tid < 128) {
            int m = tid >> 3, q = tid & 7;
            ull v = *reinterpret_cast<const ull*>(&Hp16[m][q * 4]);
            __hip_atomic_store(reinterpret_cast<ull*>(
                                   &hbuf[hbF_idx(pn, grp, m, slice * UPB + q * 4)]),
                               v, __ATOMIC_RELAXED, __HIP_MEMORY_SCOPE_AGENT);
        }
        asm volatile("s_waitcnt vmcnt(0)" ::: "memory");
        __syncthreads();
        if (tid == 0)
            __hip_atomic_store(&fl[(t + 1) * NSLICE + slice], 1u,
                               __ATOMIC_RELAXED, __HIP_MEMORY_SCOPE_AGENT);
        if (tid >= 128 && tid < 256) {
            int j = tid - 128;
            int m = j >> 3, q = j & 7;
            float4 v = *reinterpret_cast<const float4*>(&Hpf[m][q * 4]);
            *reinterpret_cast<float4*>(
                &out[((size_t)(grp * GB + m) * Tdim + t) * Hdim + slice * UPB + q * 4]) = v;
        }
    }
    if (g == 0) {
        const size_t fsz = (size_t)(NGRP * GB) * Tdim * Hdim;
        #pragma unroll
        for (int r = 0; r < 4; ++r) {
            int m = lhi * 4 + r;
            out[fsz + (size_t)(grp * GB + m) * Hdim + u] = hv[r];
            out[fsz + (size_t)(NGRP * GB) * Hdim + (size_t)(grp * GB + m) * Hdim + u] = c_reg[r];
        }
    }
}

extern "C" void kernel_launch(void* const* d_in, const int* in_sizes, int n_in,
                              void* d_out, int out_size, void* d_ws, size_t ws_size,
                              hipStream_t stream) {
    const float* x    = (const float*)d_in[0];
    const float* h0   = (const float*)d_in[1];
    const float* c0   = (const float*)d_in[2];
    const float* wx   = (const float*)d_in[3];
    const float* wh   = (const float*)d_in[4];
    const float* bias = (const float*)d_in[5];
    float* out = (float*)d_out;

    if (ws_size >= WS_NEEDED) {
        uint32_t* flags = (uint32_t*)d_ws;
        ull* hbuf = (ull*)((char*)d_ws + HB_OFF);
        ull* xgp  = (ull*)((char*)d_ws + XG_OFF);
        hipMemsetAsync(d_ws, 0, FL_BYTES, stream);
        xw_gemm<<<256, 512, 0, stream>>>(x, wx, bias, xgp);
        void* args[] = {(void*)&h0, (void*)&c0, (void*)&wh, (void*)&out,
                        (void*)&flags, (void*)&hbuf, (void*)&xgp};
        hipLaunchCooperativeKernel((const void*)lstm_pair, dim3(16), dim3(512),
                                   args, 0, stream);
    } else {
        uint32_t* flags = (uint32_t*)d_ws;
        uint16_t* hbuf  = (uint16_t*)((char*)d_ws + FB_HBUF_OFF);
        hipMemsetAsync(flags, 0, FB_FLAG_BYTES, stream);
        void* args[] = {(void*)&x, (void*)&h0, (void*)&c0, (void*)&wx, (void*)&wh,
                        (void*)&bias, (void*)&out, (void*)&flags, (void*)&hbuf};
        hipLaunchCooperativeKernel((const void*)lstm_fallback, dim3(NSLICE * NGRP),
                                   dim3(NTHREADS), args, 0, stream);
    }
}